// Round 2
// baseline (5709.874 us; speedup 1.0000x reference)
//
#include <hip/hip_runtime.h>

#define IMG 1024

__device__ __forceinline__ int refl(int i) {
    i = (i < 0) ? -i : i;
    return (i >= IMG) ? (2 * IMG - 2 - i) : i;
}
__device__ __forceinline__ float afix(float a) { return (a < 0.001f) ? 1.0f : a; }
__device__ __forceinline__ int iclamp(int v, int lo, int hi) { return v < lo ? lo : (v > hi ? hi : v); }

// ---------------------------------------------------------------------------
// conv1: 12 -> 32, 7x7, reflect pad 3, ReLU. Fuses the net_in transform
// (color/albedo fix) while staging from d_in. Tile 64x8, 256 thr,
// per-thread 8 px * 8 oc. IC chunk = 2 (6 chunks).
// ---------------------------------------------------------------------------
__global__ __launch_bounds__(256, 2) void conv1_kernel(
    const float* __restrict__ in, const float* __restrict__ w1, const float* __restrict__ b1,
    float* __restrict__ h1, int ylo, int yhi, int rows1)
{
    __shared__ __align__(16) float sIn[2][14][72];
    __shared__ __align__(16) float sW[2][7][7][32];
    const int t = threadIdx.x;
    const int tx = t & 7, ocg = (t >> 3) & 3, ty = t >> 5;
    const int x0 = blockIdx.x * 64;
    const int y0 = ylo + blockIdx.y * 8;

    float acc[8][8];
#pragma unroll
    for (int o = 0; o < 8; o++)
#pragma unroll
        for (int p = 0; p < 8; p++) acc[o][p] = 0.f;

    for (int cb = 0; cb < 12; cb += 2) {
        __syncthreads();
        for (int e = t; e < 2 * 14 * 70; e += 256) {
            int ch = e / (14 * 70), rem = e % (14 * 70);
            int r = rem / 70, cc = rem % 70;
            int gy = refl(y0 + r - 3), gx = refl(x0 + cc - 3);
            size_t base = (size_t)gy * IMG + gx;
            int ic = cb + ch;
            float v;
            if (ic < 3) {
                float a = afix(in[(size_t)(ic + 3) * IMG * IMG + base]);
                v = in[(size_t)ic * IMG * IMG + base] / a;
            } else if (ic < 6) {
                v = afix(in[(size_t)ic * IMG * IMG + base]);
            } else {
                v = in[(size_t)ic * IMG * IMG + base];
            }
            sIn[ch][r][cc] = v;
        }
        for (int e = t; e < 2 * 49 * 32; e += 256) {
            int oc = e & 31, rem = e >> 5;
            int ch = rem / 49, kk = rem % 49;
            sW[ch][kk / 7][kk % 7][oc] = w1[((size_t)oc * 12 + cb + ch) * 49 + kk];
        }
        __syncthreads();
#pragma unroll 1
        for (int ch = 0; ch < 2; ch++) {
#pragma unroll 1
            for (int ky = 0; ky < 7; ky++) {
                float iv[16];
                const float4* rp = (const float4*)&sIn[ch][ty + ky][tx * 8];
                *(float4*)&iv[0] = rp[0];  *(float4*)&iv[4] = rp[1];
                *(float4*)&iv[8] = rp[2];  *(float4*)&iv[12] = rp[3];
#pragma unroll
                for (int kx = 0; kx < 7; kx++) {
                    const float4* wp = (const float4*)&sW[ch][ky][kx][ocg * 8];
                    float4 wa = wp[0], wb = wp[1];
                    float w8[8] = {wa.x, wa.y, wa.z, wa.w, wb.x, wb.y, wb.z, wb.w};
#pragma unroll
                    for (int o = 0; o < 8; o++)
#pragma unroll
                        for (int p = 0; p < 8; p++) acc[o][p] = fmaf(w8[o], iv[kx + p], acc[o][p]);
                }
            }
        }
    }
    const int y = y0 + ty;
    if (y < yhi) {
#pragma unroll
        for (int o = 0; o < 8; o++) {
            int oc = ocg * 8 + o;
            float bb = b1[oc];
            float* dst = h1 + ((size_t)oc * rows1 + (y - ylo)) * IMG + x0 + tx * 8;
            float4 v0 = make_float4(fmaxf(acc[o][0] + bb, 0.f), fmaxf(acc[o][1] + bb, 0.f),
                                    fmaxf(acc[o][2] + bb, 0.f), fmaxf(acc[o][3] + bb, 0.f));
            float4 v1 = make_float4(fmaxf(acc[o][4] + bb, 0.f), fmaxf(acc[o][5] + bb, 0.f),
                                    fmaxf(acc[o][6] + bb, 0.f), fmaxf(acc[o][7] + bb, 0.f));
            reinterpret_cast<float4*>(dst)[0] = v0;
            reinterpret_cast<float4*>(dst)[1] = v1;
        }
    }
}

// ---------------------------------------------------------------------------
// conv2: 32 -> 32, 5x5, reflect pad 2, ReLU. Tile 64x8. IC chunk = 4.
// ---------------------------------------------------------------------------
__global__ __launch_bounds__(256, 2) void conv2_kernel(
    const float* __restrict__ h1, const float* __restrict__ w2, const float* __restrict__ b2,
    float* __restrict__ h2, int in_lo, int in_hi, int rows1, int ylo, int yhi, int rows2)
{
    __shared__ __align__(16) float sIn[4][12][72];
    __shared__ __align__(16) float sW[4][5][5][32];
    const int t = threadIdx.x;
    const int tx = t & 7, ocg = (t >> 3) & 3, ty = t >> 5;
    const int x0 = blockIdx.x * 64;
    const int y0 = ylo + blockIdx.y * 8;

    float acc[8][8];
#pragma unroll
    for (int o = 0; o < 8; o++)
#pragma unroll
        for (int p = 0; p < 8; p++) acc[o][p] = 0.f;

    for (int cb = 0; cb < 32; cb += 4) {
        __syncthreads();
        for (int e = t; e < 4 * 12 * 68; e += 256) {
            int ch = e / (12 * 68), rem = e % (12 * 68);
            int r = rem / 68, cc = rem % 68;
            int gy = iclamp(refl(y0 + r - 2), in_lo, in_hi - 1);
            int gx = refl(x0 + cc - 2);
            sIn[ch][r][cc] = h1[((size_t)(cb + ch) * rows1 + (gy - in_lo)) * IMG + gx];
        }
        for (int e = t; e < 4 * 25 * 32; e += 256) {
            int oc = e & 31, rem = e >> 5;
            int ch = rem / 25, kk = rem % 25;
            sW[ch][kk / 5][kk % 5][oc] = w2[((size_t)oc * 32 + cb + ch) * 25 + kk];
        }
        __syncthreads();
#pragma unroll 1
        for (int ch = 0; ch < 4; ch++) {
#pragma unroll 1
            for (int ky = 0; ky < 5; ky++) {
                float iv[12];
                const float4* rp = (const float4*)&sIn[ch][ty + ky][tx * 8];
                *(float4*)&iv[0] = rp[0];  *(float4*)&iv[4] = rp[1];  *(float4*)&iv[8] = rp[2];
#pragma unroll
                for (int kx = 0; kx < 5; kx++) {
                    const float4* wp = (const float4*)&sW[ch][ky][kx][ocg * 8];
                    float4 wa = wp[0], wb = wp[1];
                    float w8[8] = {wa.x, wa.y, wa.z, wa.w, wb.x, wb.y, wb.z, wb.w};
#pragma unroll
                    for (int o = 0; o < 8; o++)
#pragma unroll
                        for (int p = 0; p < 8; p++) acc[o][p] = fmaf(w8[o], iv[kx + p], acc[o][p]);
                }
            }
        }
    }
    const int y = y0 + ty;
    if (y < yhi) {
#pragma unroll
        for (int o = 0; o < 8; o++) {
            int oc = ocg * 8 + o;
            float bb = b2[oc];
            float* dst = h2 + ((size_t)oc * rows2 + (y - ylo)) * IMG + x0 + tx * 8;
            float4 v0 = make_float4(fmaxf(acc[o][0] + bb, 0.f), fmaxf(acc[o][1] + bb, 0.f),
                                    fmaxf(acc[o][2] + bb, 0.f), fmaxf(acc[o][3] + bb, 0.f));
            float4 v1 = make_float4(fmaxf(acc[o][4] + bb, 0.f), fmaxf(acc[o][5] + bb, 0.f),
                                    fmaxf(acc[o][6] + bb, 0.f), fmaxf(acc[o][7] + bb, 0.f));
            reinterpret_cast<float4*>(dst)[0] = v0;
            reinterpret_cast<float4*>(dst)[1] = v1;
        }
    }
}

// ---------------------------------------------------------------------------
// conv3: 32 -> 8, 5x5, reflect pad 2, no relu. Tile 128x16, 256 thr,
// per-thread 8 px * all 8 oc. IC chunk = 4.
// ---------------------------------------------------------------------------
__global__ __launch_bounds__(256, 2) void conv3_kernel(
    const float* __restrict__ h2, const float* __restrict__ w3, const float* __restrict__ b3,
    float* __restrict__ lg, int in_lo, int in_hi, int rows2, int ylo, int yhi, int rowsL)
{
    __shared__ __align__(16) float sIn[4][20][136];
    __shared__ __align__(16) float sW[4][5][5][8];
    const int t = threadIdx.x;
    const int tx = t & 15, ty = t >> 4;
    const int x0 = blockIdx.x * 128;
    const int y0 = ylo + blockIdx.y * 16;

    float acc[8][8];
#pragma unroll
    for (int o = 0; o < 8; o++)
#pragma unroll
        for (int p = 0; p < 8; p++) acc[o][p] = 0.f;

    for (int cb = 0; cb < 32; cb += 4) {
        __syncthreads();
        for (int e = t; e < 4 * 20 * 132; e += 256) {
            int ch = e / (20 * 132), rem = e % (20 * 132);
            int r = rem / 132, cc = rem % 132;
            int gy = iclamp(refl(y0 + r - 2), in_lo, in_hi - 1);
            int gx = refl(x0 + cc - 2);
            sIn[ch][r][cc] = h2[((size_t)(cb + ch) * rows2 + (gy - in_lo)) * IMG + gx];
        }
        for (int e = t; e < 4 * 25 * 8; e += 256) {
            int oc = e & 7, rem = e >> 3;
            int ch = rem / 25, kk = rem % 25;
            sW[ch][kk / 5][kk % 5][oc] = w3[((size_t)oc * 32 + cb + ch) * 25 + kk];
        }
        __syncthreads();
#pragma unroll 1
        for (int ch = 0; ch < 4; ch++) {
#pragma unroll 1
            for (int ky = 0; ky < 5; ky++) {
                float iv[16];
                const float4* rp = (const float4*)&sIn[ch][ty + ky][tx * 8];
                *(float4*)&iv[0] = rp[0];  *(float4*)&iv[4] = rp[1];
                *(float4*)&iv[8] = rp[2];  *(float4*)&iv[12] = rp[3];
#pragma unroll
                for (int kx = 0; kx < 5; kx++) {
                    const float4* wp = (const float4*)&sW[ch][ky][kx][0];
                    float4 wa = wp[0], wb = wp[1];
                    float w8[8] = {wa.x, wa.y, wa.z, wa.w, wb.x, wb.y, wb.z, wb.w};
#pragma unroll
                    for (int o = 0; o < 8; o++)
#pragma unroll
                        for (int p = 0; p < 8; p++) acc[o][p] = fmaf(w8[o], iv[kx + p], acc[o][p]);
                }
            }
        }
    }
    const int y = y0 + ty;
    if (y < yhi) {
#pragma unroll
        for (int o = 0; o < 8; o++) {
            float bb = b3[o];
            float* dst = lg + ((size_t)o * rowsL + (y - ylo)) * IMG + x0 + tx * 8;
            float4 v0 = make_float4(acc[o][0] + bb, acc[o][1] + bb, acc[o][2] + bb, acc[o][3] + bb);
            float4 v1 = make_float4(acc[o][4] + bb, acc[o][5] + bb, acc[o][6] + bb, acc[o][7] + bb);
            reinterpret_cast<float4*>(dst)[0] = v0;
            reinterpret_cast<float4*>(dst)[1] = v1;
        }
    }
}

// ---------------------------------------------------------------------------
// final: softmax(logits/5) + depthwise 7x7 zero-pad preconv of color +
// weighted sum + albedo remodulate. Tile 64x16, 256 thr, 4 px/thread.
// ---------------------------------------------------------------------------
__global__ __launch_bounds__(256, 2) void final_kernel(
    const float* __restrict__ in, const float* __restrict__ lg, const float* __restrict__ dw,
    float* __restrict__ outp, int ylo, int yhi, int rowsL)
{
    __shared__ __align__(16) float sC[3][22][72];
    __shared__ __align__(16) float sdw[8][49];
    const int t = threadIdx.x;
    const int tx = t & 15, ty = t >> 4;
    const int x0 = blockIdx.x * 64;
    const int y0 = ylo + blockIdx.y * 16;

    for (int e = t; e < 8 * 49; e += 256) sdw[e / 49][e % 49] = dw[e];
    for (int e = t; e < 3 * 22 * 70; e += 256) {
        int c = e / (22 * 70), rem = e % (22 * 70);
        int r = rem / 70, cc = rem % 70;
        int gy = y0 + r - 3, gx = x0 + cc - 3;
        float v = 0.f;
        if (gy >= 0 && gy < IMG && gx >= 0 && gx < IMG) {
            float a = afix(in[(size_t)(c + 3) * IMG * IMG + (size_t)gy * IMG + gx]);
            v = in[(size_t)c * IMG * IMG + (size_t)gy * IMG + gx] / a;
        }
        sC[c][r][cc] = v;
    }
    __syncthreads();
    const int y = y0 + ty;
    if (y >= yhi) return;

    // softmax over 8 logit channels for 4 pixels
    float l[4][8];
#pragma unroll
    for (int k = 0; k < 8; k++) {
        float4 v = *(const float4*)&lg[((size_t)k * rowsL + (y - ylo)) * IMG + x0 + tx * 4];
        l[0][k] = v.x; l[1][k] = v.y; l[2][k] = v.z; l[3][k] = v.w;
    }
    float p[4][8];
#pragma unroll
    for (int j = 0; j < 4; j++) {
        float m = -3.4e38f;
#pragma unroll
        for (int k = 0; k < 8; k++) m = fmaxf(m, l[j][k]);
        float s = 0.f;
#pragma unroll
        for (int k = 0; k < 8; k++) { float ev = __expf((l[j][k] - m) * 0.2f); p[j][k] = ev; s += ev; }
        float invs = 1.0f / s;
#pragma unroll
        for (int k = 0; k < 8; k++) p[j][k] *= invs;
    }

    float filt[3][4];
#pragma unroll
    for (int c = 0; c < 3; c++)
#pragma unroll
        for (int j = 0; j < 4; j++) filt[c][j] = 0.f;

#pragma unroll 1
    for (int ky = 0; ky < 7; ky++) {
        float cv[3][10];
#pragma unroll
        for (int c = 0; c < 3; c++)
#pragma unroll
            for (int jj = 0; jj < 10; jj++) cv[c][jj] = sC[c][ty + ky][tx * 4 + jj];
#pragma unroll
        for (int kx = 0; kx < 7; kx++) {
            float dwv[8];
#pragma unroll
            for (int k = 0; k < 8; k++) dwv[k] = sdw[k][ky * 7 + kx];
#pragma unroll
            for (int j = 0; j < 4; j++) {
                float e0 = 0.f;
#pragma unroll
                for (int k = 0; k < 8; k++) e0 = fmaf(p[j][k], dwv[k], e0);
#pragma unroll
                for (int c = 0; c < 3; c++) filt[c][j] = fmaf(e0, cv[c][kx + j], filt[c][j]);
            }
        }
    }
#pragma unroll
    for (int c = 0; c < 3; c++) {
        const float* ap = &in[(size_t)(c + 3) * IMG * IMG + (size_t)y * IMG + x0 + tx * 4];
        float4 a4 = *(const float4*)ap;
        float4 o4 = make_float4(afix(a4.x) * filt[c][0], afix(a4.y) * filt[c][1],
                                afix(a4.z) * filt[c][2], afix(a4.w) * filt[c][3]);
        *(float4*)&outp[(size_t)c * IMG * IMG + (size_t)y * IMG + x0 + tx * 4] = o4;
    }
}

// ---------------------------------------------------------------------------
extern "C" void kernel_launch(void* const* d_in, const int* in_sizes, int n_in,
                              void* d_out, int out_size, void* d_ws, size_t ws_size,
                              hipStream_t stream)
{
    const float* in  = (const float*)d_in[0];
    const float* w1  = (const float*)d_in[1];
    const float* b1  = (const float*)d_in[2];
    const float* w2  = (const float*)d_in[3];
    const float* b2  = (const float*)d_in[4];
    const float* w3  = (const float*)d_in[5];
    const float* b3  = (const float*)d_in[6];
    const float* dw  = (const float*)d_in[7];
    float* out = (float*)d_out;

    // pick largest row-stripe S whose h1/h2/logits buffers fit in ws
    int S = 1024;
    while (S > 32) {
        size_t need = 4ull * IMG * ((size_t)(S + 8) * 32 + (size_t)(S + 4) * 32 + (size_t)S * 8);
        if (need <= ws_size) break;
        S >>= 1;
    }
    const int rows1 = S + 8, rows2 = S + 4, rowsL = S;
    float* h1  = (float*)d_ws;
    float* h2  = h1 + (size_t)32 * rows1 * IMG;
    float* lgb = h2 + (size_t)32 * rows2 * IMG;

    for (int b = 0; b < 4; b++) {
        const float* inb = in + (size_t)b * 12 * IMG * IMG;
        float* outb = out + (size_t)b * 3 * IMG * IMG;
        for (int r0 = 0; r0 < IMG; r0 += S) {
            int r1 = r0 + S; if (r1 > IMG) r1 = IMG;
            int a1 = r0 - 4; if (a1 < 0) a1 = 0;
            int e1 = r1 + 4; if (e1 > IMG) e1 = IMG;
            int a2 = r0 - 2; if (a2 < 0) a2 = 0;
            int e2 = r1 + 2; if (e2 > IMG) e2 = IMG;
            conv1_kernel<<<dim3(16, (e1 - a1 + 7) / 8), 256, 0, stream>>>(inb, w1, b1, h1, a1, e1, rows1);
            conv2_kernel<<<dim3(16, (e2 - a2 + 7) / 8), 256, 0, stream>>>(h1, w2, b2, h2, a1, e1, rows1, a2, e2, rows2);
            conv3_kernel<<<dim3(8, (r1 - r0 + 15) / 16), 256, 0, stream>>>(h2, w3, b3, lgb, a2, e2, rows2, r0, r1, rowsL);
            final_kernel<<<dim3(16, (r1 - r0 + 15) / 16), 256, 0, stream>>>(inb, lgb, dw, outb, r0, r1, rowsL);
        }
    }
}

// Round 3
// 2271.628 us; speedup vs baseline: 2.5136x; 2.5136x over previous
//
#include <hip/hip_runtime.h>

#define IMG 1024

typedef _Float16 half8 __attribute__((ext_vector_type(8)));
typedef float f32x4 __attribute__((ext_vector_type(4)));

__device__ __forceinline__ int refl(int i) {
    i = (i < 0) ? -i : i;
    return (i >= IMG) ? (2 * IMG - 2 - i) : i;
}
__device__ __forceinline__ float afix(float a) { return (a < 0.001f) ? 1.0f : a; }
__device__ __forceinline__ int iclamp(int v, int lo, int hi) { return v < lo ? lo : (v > hi ? hi : v); }
// LDS swizzles (involutions; write & read use the same). Derived for
// ds_read_b128 patterns: 64B/px -> <=2-way conflicts, 32B/px -> <=2-way.
__device__ __forceinline__ int swz64(int a) { return a ^ (((((a >> 6) & 3) ^ ((a >> 8) & 1)) << 4)); }
__device__ __forceinline__ int swz32(int a) { return a ^ ((((a >> 7) & 1)) << 4); }
__device__ __forceinline__ unsigned short h2b(_Float16 h) { union { _Float16 f; unsigned short u; } x; x.f = h; return x.u; }

// ---------------------------------------------------------------------------
// Weight prep: pack w1/w2/w3 into MFMA A-fragments (16 oc x 32 k), fp16 hi/lo.
// Frag = 1024B: lane l (64) x 8 fp16. A mapping: row(oc)=l&15, k=(l>>4)*8+e.
// conv1: k = (kx'=k>>4 within pair)*16? -> kx = 2j + (k>>4), ic = k&15 (ic pad 12->16)
// conv2: k = ic (0..31).  conv3: k = ic, oc padded 8->16 (zeros).
// ---------------------------------------------------------------------------
__global__ void wprep_kernel(const float* __restrict__ w1, const float* __restrict__ w2,
                             const float* __restrict__ w3,
                             char* __restrict__ w1p, char* __restrict__ w2p, char* __restrict__ w3p)
{
    const int NF1 = 7 * 2 * 4 * 2, NF2 = 5 * 2 * 5 * 2, NF3 = 5 * 5 * 2;
    int gid = blockIdx.x * 256 + threadIdx.x;
    int f = gid >> 6, l = gid & 63;
    if (f >= NF1 + NF2 + NF3) return;
    int r = l & 15, g = l >> 4;
    half8 out;
    char* dst;
    if (f < NF1) {
        int pl = f & 1, j = (f >> 1) & 3, oct = (f >> 3) & 1, ky = f >> 4;
        int oc = oct * 16 + r;
#pragma unroll
        for (int e = 0; e < 8; e++) {
            int k = g * 8 + e, kx = 2 * j + (k >> 4), ic = k & 15;
            float v = (ic < 12 && kx < 7) ? w1[((oc * 12 + ic) * 7 + ky) * 7 + kx] : 0.f;
            _Float16 h = (_Float16)v;
            out[e] = pl ? (_Float16)(v - (float)h) : h;
        }
        dst = w1p + (size_t)f * 1024 + l * 16;
    } else if (f < NF1 + NF2) {
        int ff = f - NF1;
        int pl = ff & 1, t2 = ff >> 1;
        int kx = t2 % 5; t2 /= 5;
        int oct = t2 & 1, ky = t2 >> 1;
        int oc = oct * 16 + r;
#pragma unroll
        for (int e = 0; e < 8; e++) {
            int ic = g * 8 + e;
            float v = w2[((oc * 32 + ic) * 5 + ky) * 5 + kx];
            _Float16 h = (_Float16)v;
            out[e] = pl ? (_Float16)(v - (float)h) : h;
        }
        dst = w2p + (size_t)ff * 1024 + l * 16;
    } else {
        int ff = f - NF1 - NF2;
        int pl = ff & 1, t2 = ff >> 1;
        int kx = t2 % 5, ky = t2 / 5;
#pragma unroll
        for (int e = 0; e < 8; e++) {
            int ic = g * 8 + e;
            float v = (r < 8) ? w3[((r * 32 + ic) * 5 + ky) * 5 + kx] : 0.f;
            _Float16 h = (_Float16)v;
            out[e] = pl ? (_Float16)(v - (float)h) : h;
        }
        dst = w3p + (size_t)ff * 1024 + l * 16;
    }
    *(half8*)dst = out;
}

// ---------------------------------------------------------------------------
// net_in prep (per image): transform + scale 1/4 + fp16 hi/lo split.
// Layout: [y][x][16ch] per plane (32B/px/plane).
// ---------------------------------------------------------------------------
__global__ void netin_kernel(const float* __restrict__ in, char* __restrict__ nh, char* __restrict__ nl)
{
    const int M = IMG * IMG;
    int px = blockIdx.x * 256 + threadIdx.x;
    float v[16];
#pragma unroll
    for (int c = 0; c < 3; c++) {
        float a = afix(in[(size_t)(c + 3) * M + px]);
        v[c] = (in[(size_t)c * M + px] / a) * 0.25f;
        v[c + 3] = a * 0.25f;
    }
#pragma unroll
    for (int c = 6; c < 12; c++) v[c] = in[(size_t)c * M + px] * 0.25f;
#pragma unroll
    for (int c = 12; c < 16; c++) v[c] = 0.f;
    unsigned short hb[16], lb[16];
#pragma unroll
    for (int c = 0; c < 16; c++) {
        _Float16 h = (_Float16)v[c];
        hb[c] = h2b(h);
        lb[c] = h2b((_Float16)(v[c] - (float)h));
    }
    *(int4*)(nh + (size_t)px * 32) = *(int4*)&hb[0];
    *(int4*)(nh + (size_t)px * 32 + 16) = *(int4*)&hb[8];
    *(int4*)(nl + (size_t)px * 32) = *(int4*)&lb[0];
    *(int4*)(nl + (size_t)px * 32 + 16) = *(int4*)&lb[8];
}

// ---------------------------------------------------------------------------
// conv1 MFMA: 12(pad16) -> 32, 7x7 reflect. K=32 = (kx pair)x16ic, 4 j-steps.
// Block 256thr/4 waves, tile 32px x 8 rows. Wave: 16px x 32oc x 4 rows.
// ---------------------------------------------------------------------------
__global__ __launch_bounds__(256, 2) void conv1_mfma(
    const char* __restrict__ nh, const char* __restrict__ nl,
    const char* __restrict__ w1p, const float* __restrict__ b1,
    char* __restrict__ h1h, char* __restrict__ h1l, int a1, int e1)
{
    __shared__ __align__(16) char sm[2 * 14 * 1280];  // 14 slabs x 40px x 32B, 2 planes
    const int t = threadIdx.x, l = t & 63, w = t >> 6;
    const int c = l & 15, g = l >> 4;
    const int x0 = blockIdx.x * 32;
    const int ystart = a1 + blockIdx.y * 8;

    for (int q = t; q < 2240; q += 256) {
        int pl = q / 1120, rem = q % 1120;
        int slab = rem / 80, c2 = rem % 80;
        int px = c2 >> 1, s = c2 & 1;
        int gy = refl(ystart + slab - 3);
        int gx = refl(x0 + px - 3);
        const char* src = (pl ? nl : nh) + ((size_t)gy * IMG + gx) * 32 + s * 16;
        *(int4*)(sm + pl * 17920 + slab * 1280 + swz32(px * 32 + s * 16)) = *(const int4*)src;
    }
    __syncthreads();

    f32x4 zero4 = {0.f, 0.f, 0.f, 0.f};
    f32x4 acc[2][4];
#pragma unroll
    for (int o = 0; o < 2; o++)
#pragma unroll
        for (int r = 0; r < 4; r++) acc[o][r] = zero4;

    const int pxt = w & 1, rbase = (w >> 1) * 4;
#pragma unroll 1
    for (int ky = 0; ky < 7; ky++) {
        half8 aw[2][4][2];
#pragma unroll
        for (int oct = 0; oct < 2; oct++)
#pragma unroll
            for (int j = 0; j < 4; j++)
#pragma unroll
                for (int pl = 0; pl < 2; pl++)
                    aw[oct][j][pl] = *(const half8*)(w1p + (size_t)((((ky * 2 + oct) * 4 + j) * 2 + pl)) * 1024 + l * 16);
#pragma unroll
        for (int r = 0; r < 4; r++) {
            const char* base = sm + (rbase + r + ky) * 1280;
#pragma unroll
            for (int j = 0; j < 4; j++) {
                int p2 = pxt * 16 + c + 2 * j + (g >> 1);
                int off = swz32(p2 * 32 + (g & 1) * 16);
                half8 bh = *(const half8*)(base + off);
                half8 bl = *(const half8*)(base + 17920 + off);
#pragma unroll
                for (int oct = 0; oct < 2; oct++) {
                    acc[oct][r] = __builtin_amdgcn_mfma_f32_16x16x32_f16(aw[oct][j][0], bh, acc[oct][r], 0, 0, 0);
                    acc[oct][r] = __builtin_amdgcn_mfma_f32_16x16x32_f16(aw[oct][j][0], bl, acc[oct][r], 0, 0, 0);
                    acc[oct][r] = __builtin_amdgcn_mfma_f32_16x16x32_f16(aw[oct][j][1], bh, acc[oct][r], 0, 0, 0);
                }
            }
        }
    }
#pragma unroll
    for (int r = 0; r < 4; r++) {
        int y = ystart + rbase + r;
        if (y < e1) {
            int x = x0 + pxt * 16 + c, ybuf = y - a1;
#pragma unroll
            for (int oct = 0; oct < 2; oct++) {
                ushort4 hv, lv;
                float vv[4];
#pragma unroll
                for (int i = 0; i < 4; i++) {
                    int oc = oct * 16 + g * 4 + i;
                    float v = acc[oct][r][i] * 4.f + b1[oc];
                    vv[i] = fmaxf(v, 0.f) * 0.125f;
                }
                _Float16 h0 = (_Float16)vv[0], h1_ = (_Float16)vv[1], h2_ = (_Float16)vv[2], h3 = (_Float16)vv[3];
                hv.x = h2b(h0); hv.y = h2b(h1_); hv.z = h2b(h2_); hv.w = h2b(h3);
                lv.x = h2b((_Float16)(vv[0] - (float)h0)); lv.y = h2b((_Float16)(vv[1] - (float)h1_));
                lv.z = h2b((_Float16)(vv[2] - (float)h2_)); lv.w = h2b((_Float16)(vv[3] - (float)h3));
                size_t ob = ((size_t)ybuf * IMG + x) * 64 + oct * 32 + g * 8;
                *(ushort4*)(h1h + ob) = hv;
                *(ushort4*)(h1l + ob) = lv;
            }
        }
    }
}

// ---------------------------------------------------------------------------
// conv2 MFMA: 32 -> 32, 5x5 reflect. K=32=ic per (ky,kx).
// ---------------------------------------------------------------------------
__global__ __launch_bounds__(256, 2) void conv2_mfma(
    const char* __restrict__ h1h, const char* __restrict__ h1l,
    const char* __restrict__ w2p, const float* __restrict__ b2,
    char* __restrict__ h2h, char* __restrict__ h2l,
    int a1, int e1, int a2, int e2)
{
    __shared__ __align__(16) char sm[2 * 12 * 2304];  // 12 slabs x 36px x 64B, 2 planes
    const int t = threadIdx.x, l = t & 63, w = t >> 6;
    const int c = l & 15, g = l >> 4;
    const int x0 = blockIdx.x * 32;
    const int ystart = a2 + blockIdx.y * 8;

    for (int q = t; q < 3456; q += 256) {
        int pl = q / 1728, rem = q % 1728;
        int slab = rem / 144, c2 = rem % 144;
        int px = c2 >> 2, s = c2 & 3;
        int yy = iclamp(refl(ystart + slab - 2), a1, e1 - 1) - a1;
        int gx = refl(x0 + px - 2);
        const char* src = (pl ? h1l : h1h) + ((size_t)yy * IMG + gx) * 64 + s * 16;
        *(int4*)(sm + pl * 27648 + slab * 2304 + swz64(px * 64 + s * 16)) = *(const int4*)src;
    }
    __syncthreads();

    f32x4 zero4 = {0.f, 0.f, 0.f, 0.f};
    f32x4 acc[2][4];
#pragma unroll
    for (int o = 0; o < 2; o++)
#pragma unroll
        for (int r = 0; r < 4; r++) acc[o][r] = zero4;

    const int pxt = w & 1, rbase = (w >> 1) * 4;
#pragma unroll 1
    for (int ky = 0; ky < 5; ky++) {
        half8 aw[2][5][2];
#pragma unroll
        for (int oct = 0; oct < 2; oct++)
#pragma unroll
            for (int kx = 0; kx < 5; kx++)
#pragma unroll
                for (int pl = 0; pl < 2; pl++)
                    aw[oct][kx][pl] = *(const half8*)(w2p + (size_t)((((ky * 2 + oct) * 5 + kx) * 2 + pl)) * 1024 + l * 16);
#pragma unroll
        for (int r = 0; r < 4; r++) {
            const char* base = sm + (rbase + r + ky) * 2304;
#pragma unroll
            for (int kx = 0; kx < 5; kx++) {
                int p = pxt * 16 + c + kx;
                int off = swz64(p * 64 + g * 16);
                half8 bh = *(const half8*)(base + off);
                half8 bl = *(const half8*)(base + 27648 + off);
#pragma unroll
                for (int oct = 0; oct < 2; oct++) {
                    acc[oct][r] = __builtin_amdgcn_mfma_f32_16x16x32_f16(aw[oct][kx][0], bh, acc[oct][r], 0, 0, 0);
                    acc[oct][r] = __builtin_amdgcn_mfma_f32_16x16x32_f16(aw[oct][kx][0], bl, acc[oct][r], 0, 0, 0);
                    acc[oct][r] = __builtin_amdgcn_mfma_f32_16x16x32_f16(aw[oct][kx][1], bh, acc[oct][r], 0, 0, 0);
                }
            }
        }
    }
#pragma unroll
    for (int r = 0; r < 4; r++) {
        int y = ystart + rbase + r;
        if (y < e2) {
            int x = x0 + pxt * 16 + c, ybuf = y - a2;
#pragma unroll
            for (int oct = 0; oct < 2; oct++) {
                ushort4 hv, lv;
                float vv[4];
#pragma unroll
                for (int i = 0; i < 4; i++) {
                    int oc = oct * 16 + g * 4 + i;
                    float v = acc[oct][r][i] * 8.f + b2[oc];
                    vv[i] = fmaxf(v, 0.f) * 0.125f;
                }
                _Float16 h0 = (_Float16)vv[0], h1_ = (_Float16)vv[1], h2_ = (_Float16)vv[2], h3 = (_Float16)vv[3];
                hv.x = h2b(h0); hv.y = h2b(h1_); hv.z = h2b(h2_); hv.w = h2b(h3);
                lv.x = h2b((_Float16)(vv[0] - (float)h0)); lv.y = h2b((_Float16)(vv[1] - (float)h1_));
                lv.z = h2b((_Float16)(vv[2] - (float)h2_)); lv.w = h2b((_Float16)(vv[3] - (float)h3));
                size_t ob = ((size_t)ybuf * IMG + x) * 64 + oct * 32 + g * 8;
                *(ushort4*)(h2h + ob) = hv;
                *(ushort4*)(h2l + ob) = lv;
            }
        }
    }
}

// ---------------------------------------------------------------------------
// conv3 MFMA: 32 -> 8 (oc padded to 16), 5x5 reflect. Logits fp32 out.
// ---------------------------------------------------------------------------
__global__ __launch_bounds__(256, 2) void conv3_mfma(
    const char* __restrict__ h2h, const char* __restrict__ h2l,
    const char* __restrict__ w3p, const float* __restrict__ b3,
    float* __restrict__ lg, int a2, int e2, int r0, int r1, int rowsL)
{
    __shared__ __align__(16) char sm[2 * 12 * 2304];
    const int t = threadIdx.x, l = t & 63, w = t >> 6;
    const int c = l & 15, g = l >> 4;
    const int x0 = blockIdx.x * 32;
    const int ystart = r0 + blockIdx.y * 8;

    for (int q = t; q < 3456; q += 256) {
        int pl = q / 1728, rem = q % 1728;
        int slab = rem / 144, c2 = rem % 144;
        int px = c2 >> 2, s = c2 & 3;
        int yy = iclamp(refl(ystart + slab - 2), a2, e2 - 1) - a2;
        int gx = refl(x0 + px - 2);
        const char* src = (pl ? h2l : h2h) + ((size_t)yy * IMG + gx) * 64 + s * 16;
        *(int4*)(sm + pl * 27648 + slab * 2304 + swz64(px * 64 + s * 16)) = *(const int4*)src;
    }
    __syncthreads();

    f32x4 zero4 = {0.f, 0.f, 0.f, 0.f};
    f32x4 acc[4];
#pragma unroll
    for (int r = 0; r < 4; r++) acc[r] = zero4;

    const int pxt = w & 1, rbase = (w >> 1) * 4;
#pragma unroll 1
    for (int ky = 0; ky < 5; ky++) {
        half8 aw[5][2];
#pragma unroll
        for (int kx = 0; kx < 5; kx++)
#pragma unroll
            for (int pl = 0; pl < 2; pl++)
                aw[kx][pl] = *(const half8*)(w3p + (size_t)(((ky * 5 + kx) * 2 + pl)) * 1024 + l * 16);
#pragma unroll
        for (int r = 0; r < 4; r++) {
            const char* base = sm + (rbase + r + ky) * 2304;
#pragma unroll
            for (int kx = 0; kx < 5; kx++) {
                int p = pxt * 16 + c + kx;
                int off = swz64(p * 64 + g * 16);
                half8 bh = *(const half8*)(base + off);
                half8 bl = *(const half8*)(base + 27648 + off);
                acc[r] = __builtin_amdgcn_mfma_f32_16x16x32_f16(aw[kx][0], bh, acc[r], 0, 0, 0);
                acc[r] = __builtin_amdgcn_mfma_f32_16x16x32_f16(aw[kx][0], bl, acc[r], 0, 0, 0);
                acc[r] = __builtin_amdgcn_mfma_f32_16x16x32_f16(aw[kx][1], bh, acc[r], 0, 0, 0);
            }
        }
    }
#pragma unroll
    for (int r = 0; r < 4; r++) {
        int y = ystart + rbase + r;
        if (y < r1 && g < 2) {
            int x = x0 + pxt * 16 + c, row = y - r0;
#pragma unroll
            for (int i = 0; i < 4; i++) {
                int oc = g * 4 + i;
                lg[((size_t)oc * rowsL + row) * IMG + x] = acc[r][i] * 8.f + b3[oc];
            }
        }
    }
}

// ---------------------------------------------------------------------------
// final: softmax(logits/5) + depthwise 7x7 zero-pad preconv of color +
// weighted sum + albedo remodulate. (fp32, unchanged from baseline.)
// ---------------------------------------------------------------------------
__global__ __launch_bounds__(256, 2) void final_kernel(
    const float* __restrict__ in, const float* __restrict__ lg, const float* __restrict__ dw,
    float* __restrict__ outp, int ylo, int yhi, int rowsL)
{
    __shared__ __align__(16) float sC[3][22][72];
    __shared__ __align__(16) float sdw[8][49];
    const int t = threadIdx.x;
    const int tx = t & 15, ty = t >> 4;
    const int x0 = blockIdx.x * 64;
    const int y0 = ylo + blockIdx.y * 16;

    for (int e = t; e < 8 * 49; e += 256) sdw[e / 49][e % 49] = dw[e];
    for (int e = t; e < 3 * 22 * 70; e += 256) {
        int c = e / (22 * 70), rem = e % (22 * 70);
        int r = rem / 70, cc = rem % 70;
        int gy = y0 + r - 3, gx = x0 + cc - 3;
        float v = 0.f;
        if (gy >= 0 && gy < IMG && gx >= 0 && gx < IMG) {
            float a = afix(in[(size_t)(c + 3) * IMG * IMG + (size_t)gy * IMG + gx]);
            v = in[(size_t)c * IMG * IMG + (size_t)gy * IMG + gx] / a;
        }
        sC[c][r][cc] = v;
    }
    __syncthreads();
    const int y = y0 + ty;
    if (y >= yhi) return;

    float lv[4][8];
#pragma unroll
    for (int k = 0; k < 8; k++) {
        float4 v = *(const float4*)&lg[((size_t)k * rowsL + (y - ylo)) * IMG + x0 + tx * 4];
        lv[0][k] = v.x; lv[1][k] = v.y; lv[2][k] = v.z; lv[3][k] = v.w;
    }
    float p[4][8];
#pragma unroll
    for (int j = 0; j < 4; j++) {
        float m = -3.4e38f;
#pragma unroll
        for (int k = 0; k < 8; k++) m = fmaxf(m, lv[j][k]);
        float s = 0.f;
#pragma unroll
        for (int k = 0; k < 8; k++) { float ev = __expf((lv[j][k] - m) * 0.2f); p[j][k] = ev; s += ev; }
        float invs = 1.0f / s;
#pragma unroll
        for (int k = 0; k < 8; k++) p[j][k] *= invs;
    }

    float filt[3][4];
#pragma unroll
    for (int c = 0; c < 3; c++)
#pragma unroll
        for (int j = 0; j < 4; j++) filt[c][j] = 0.f;

#pragma unroll 1
    for (int ky = 0; ky < 7; ky++) {
        float cv[3][10];
#pragma unroll
        for (int c = 0; c < 3; c++)
#pragma unroll
            for (int jj = 0; jj < 10; jj++) cv[c][jj] = sC[c][ty + ky][tx * 4 + jj];
#pragma unroll
        for (int kx = 0; kx < 7; kx++) {
            float dwv[8];
#pragma unroll
            for (int k = 0; k < 8; k++) dwv[k] = sdw[k][ky * 7 + kx];
#pragma unroll
            for (int j = 0; j < 4; j++) {
                float e0 = 0.f;
#pragma unroll
                for (int k = 0; k < 8; k++) e0 = fmaf(p[j][k], dwv[k], e0);
#pragma unroll
                for (int c = 0; c < 3; c++) filt[c][j] = fmaf(e0, cv[c][kx + j], filt[c][j]);
            }
        }
    }
#pragma unroll
    for (int c = 0; c < 3; c++) {
        const float* ap = &in[(size_t)(c + 3) * IMG * IMG + (size_t)y * IMG + x0 + tx * 4];
        float4 a4 = *(const float4*)ap;
        float4 o4 = make_float4(afix(a4.x) * filt[c][0], afix(a4.y) * filt[c][1],
                                afix(a4.z) * filt[c][2], afix(a4.w) * filt[c][3]);
        *(float4*)&outp[(size_t)c * IMG * IMG + (size_t)y * IMG + x0 + tx * 4] = o4;
    }
}

// ---------------------------------------------------------------------------
extern "C" void kernel_launch(void* const* d_in, const int* in_sizes, int n_in,
                              void* d_out, int out_size, void* d_ws, size_t ws_size,
                              hipStream_t stream)
{
    const float* in  = (const float*)d_in[0];
    const float* w1  = (const float*)d_in[1];
    const float* b1  = (const float*)d_in[2];
    const float* w2  = (const float*)d_in[3];
    const float* b2  = (const float*)d_in[4];
    const float* w3  = (const float*)d_in[5];
    const float* b3  = (const float*)d_in[6];
    const float* dw  = (const float*)d_in[7];
    float* out = (float*)d_out;

    const size_t WB1 = 112 * 1024, WB2 = 100 * 1024, WB3 = 50 * 1024;
    const size_t NETIN = (size_t)IMG * IMG * 32;  // bytes per plane

    // pick largest row-stripe S that fits
    int S = 1024;
    while (S > 64) {
        size_t need = WB1 + WB2 + WB3 + 2 * NETIN
                    + 2ull * (S + 8) * IMG * 64 + 2ull * (S + 4) * IMG * 64
                    + (size_t)S * IMG * 8 * 4;
        if (need <= ws_size) break;
        S >>= 1;
    }
    const int rows1 = S + 8, rows2 = S + 4, rowsL = S;

    char* w1p = (char*)d_ws;
    char* w2p = w1p + WB1;
    char* w3p = w2p + WB2;
    char* nh  = w3p + WB3;
    char* nl  = nh + NETIN;
    char* h1h = nl + NETIN;
    char* h1l = h1h + (size_t)rows1 * IMG * 64;
    char* h2h = h1l + (size_t)rows1 * IMG * 64;
    char* h2l = h2h + (size_t)rows2 * IMG * 64;
    float* lgb = (float*)(h2l + (size_t)rows2 * IMG * 64);

    wprep_kernel<<<66, 256, 0, stream>>>(w1, w2, w3, w1p, w2p, w3p);

    for (int b = 0; b < 4; b++) {
        const float* inb = in + (size_t)b * 12 * IMG * IMG;
        float* outb = out + (size_t)b * 3 * IMG * IMG;
        netin_kernel<<<IMG * IMG / 256, 256, 0, stream>>>(inb, nh, nl);
        for (int r0 = 0; r0 < IMG; r0 += S) {
            int r1 = r0 + S; if (r1 > IMG) r1 = IMG;
            int a1 = r0 - 4; if (a1 < 0) a1 = 0;
            int e1 = r1 + 4; if (e1 > IMG) e1 = IMG;
            int a2 = r0 - 2; if (a2 < 0) a2 = 0;
            int e2 = r1 + 2; if (e2 > IMG) e2 = IMG;
            conv1_mfma<<<dim3(32, (e1 - a1 + 7) / 8), 256, 0, stream>>>(nh, nl, w1p, b1, h1h, h1l, a1, e1);
            conv2_mfma<<<dim3(32, (e2 - a2 + 7) / 8), 256, 0, stream>>>(h1h, h1l, w2p, b2, h2h, h2l, a1, e1, a2, e2);
            conv3_mfma<<<dim3(32, (r1 - r0 + 7) / 8), 256, 0, stream>>>(h2h, h2l, w3p, b3, lgb, a2, e2, r0, r1, rowsL);
            final_kernel<<<dim3(16, (r1 - r0 + 15) / 16), 256, 0, stream>>>(inb, lgb, dw, outb, r0, r1, rowsL);
        }
    }
}

// Round 4
// 1994.286 us; speedup vs baseline: 2.8631x; 1.1391x over previous
//
#include <hip/hip_runtime.h>

#define IMG 1024

typedef _Float16 half8 __attribute__((ext_vector_type(8)));
typedef float f32x4 __attribute__((ext_vector_type(4)));

__device__ __forceinline__ int refl(int i) {
    i = (i < 0) ? -i : i;
    return (i >= IMG) ? (2 * IMG - 2 - i) : i;
}
__device__ __forceinline__ float afix(float a) { return (a < 0.001f) ? 1.0f : a; }
__device__ __forceinline__ int iclamp(int v, int lo, int hi) { return v < lo ? lo : (v > hi ? hi : v); }
__device__ __forceinline__ int swz64(int a) { return a ^ (((((a >> 6) & 3) ^ ((a >> 8) & 1)) << 4)); }
__device__ __forceinline__ int swz32(int a) { return a ^ ((((a >> 7) & 1)) << 4); }
__device__ __forceinline__ unsigned short h2b(_Float16 h) { union { _Float16 f; unsigned short u; } x; x.f = h; return x.u; }

// ---------------------------------------------------------------------------
// Weight prep: pack w1/w2/w3 into MFMA A-fragments (16 oc x 32 k), fp16 hi/lo.
// ---------------------------------------------------------------------------
__global__ void wprep_kernel(const float* __restrict__ w1, const float* __restrict__ w2,
                             const float* __restrict__ w3,
                             char* __restrict__ w1p, char* __restrict__ w2p, char* __restrict__ w3p)
{
    const int NF1 = 7 * 2 * 4 * 2, NF2 = 5 * 2 * 5 * 2, NF3 = 5 * 5 * 2;
    int gid = blockIdx.x * 256 + threadIdx.x;
    int f = gid >> 6, l = gid & 63;
    if (f >= NF1 + NF2 + NF3) return;
    int r = l & 15, g = l >> 4;
    half8 out;
    char* dst;
    if (f < NF1) {
        int pl = f & 1, j = (f >> 1) & 3, oct = (f >> 3) & 1, ky = f >> 4;
        int oc = oct * 16 + r;
#pragma unroll
        for (int e = 0; e < 8; e++) {
            int k = g * 8 + e, kx = 2 * j + (k >> 4), ic = k & 15;
            float v = (ic < 12 && kx < 7) ? w1[((oc * 12 + ic) * 7 + ky) * 7 + kx] : 0.f;
            _Float16 h = (_Float16)v;
            out[e] = pl ? (_Float16)(v - (float)h) : h;
        }
        dst = w1p + (size_t)f * 1024 + l * 16;
    } else if (f < NF1 + NF2) {
        int ff = f - NF1;
        int pl = ff & 1, t2 = ff >> 1;
        int kx = t2 % 5; t2 /= 5;
        int oct = t2 & 1, ky = t2 >> 1;
        int oc = oct * 16 + r;
#pragma unroll
        for (int e = 0; e < 8; e++) {
            int ic = g * 8 + e;
            float v = w2[((oc * 32 + ic) * 5 + ky) * 5 + kx];
            _Float16 h = (_Float16)v;
            out[e] = pl ? (_Float16)(v - (float)h) : h;
        }
        dst = w2p + (size_t)ff * 1024 + l * 16;
    } else {
        int ff = f - NF1 - NF2;
        int pl = ff & 1, t2 = ff >> 1;
        int kx = t2 % 5, ky = t2 / 5;
#pragma unroll
        for (int e = 0; e < 8; e++) {
            int ic = g * 8 + e;
            float v = (r < 8) ? w3[((r * 32 + ic) * 5 + ky) * 5 + kx] : 0.f;
            _Float16 h = (_Float16)v;
            out[e] = pl ? (_Float16)(v - (float)h) : h;
        }
        dst = w3p + (size_t)ff * 1024 + l * 16;
    }
    *(half8*)dst = out;
}

// ---------------------------------------------------------------------------
// net_in prep (per image): transform + scale 1/4 + fp16 hi/lo split.
// ---------------------------------------------------------------------------
__global__ void netin_kernel(const float* __restrict__ in, char* __restrict__ nh, char* __restrict__ nl)
{
    const int M = IMG * IMG;
    int px = blockIdx.x * 256 + threadIdx.x;
    float v[16];
#pragma unroll
    for (int c = 0; c < 3; c++) {
        float a = afix(in[(size_t)(c + 3) * M + px]);
        v[c] = (in[(size_t)c * M + px] / a) * 0.25f;
        v[c + 3] = a * 0.25f;
    }
#pragma unroll
    for (int c = 6; c < 12; c++) v[c] = in[(size_t)c * M + px] * 0.25f;
#pragma unroll
    for (int c = 12; c < 16; c++) v[c] = 0.f;
    unsigned short hb[16], lb[16];
#pragma unroll
    for (int c = 0; c < 16; c++) {
        _Float16 h = (_Float16)v[c];
        hb[c] = h2b(h);
        lb[c] = h2b((_Float16)(v[c] - (float)h));
    }
    *(int4*)(nh + (size_t)px * 32) = *(int4*)&hb[0];
    *(int4*)(nh + (size_t)px * 32 + 16) = *(int4*)&hb[8];
    *(int4*)(nl + (size_t)px * 32) = *(int4*)&lb[0];
    *(int4*)(nl + (size_t)px * 32 + 16) = *(int4*)&lb[8];
}

// ---------------------------------------------------------------------------
// conv1 MFMA: 12(pad16) -> 32, 7x7 reflect. Two passes over ONE LDS plane
// (hi then lo) to halve LDS -> 4 blocks/CU.
// ---------------------------------------------------------------------------
__global__ __launch_bounds__(256, 4) void conv1_mfma(
    const char* __restrict__ nh, const char* __restrict__ nl,
    const char* __restrict__ w1p, const float* __restrict__ b1,
    char* __restrict__ h1h, char* __restrict__ h1l, int a1, int e1)
{
    __shared__ __align__(16) char sm[14 * 1280];  // 14 slabs x 40px x 32B, one plane
    const int t = threadIdx.x, l = t & 63, w = t >> 6;
    const int c = l & 15, g = l >> 4;
    const int x0 = blockIdx.x * 32;
    const int ystart = a1 + blockIdx.y * 8;
    const int pxt = w & 1, rbase = (w >> 1) * 4;

    f32x4 zero4 = {0.f, 0.f, 0.f, 0.f};
    f32x4 acc[2][4];
#pragma unroll
    for (int o = 0; o < 2; o++)
#pragma unroll
        for (int r = 0; r < 4; r++) acc[o][r] = zero4;

    // ---- pass 1: hi plane, terms wh*xh + wl*xh ----
    for (int q = t; q < 1120; q += 256) {
        int slab = q / 80, c2 = q % 80;
        int px = c2 >> 1, s = c2 & 1;
        int gy = refl(ystart + slab - 3);
        int gx = refl(x0 + px - 3);
        *(int4*)(sm + slab * 1280 + swz32(px * 32 + s * 16)) =
            *(const int4*)(nh + ((size_t)gy * IMG + gx) * 32 + s * 16);
    }
    __syncthreads();
#pragma unroll 1
    for (int ky = 0; ky < 7; ky++) {
        half8 aw0[2][4], aw1[2][4];
#pragma unroll
        for (int oct = 0; oct < 2; oct++)
#pragma unroll
            for (int j = 0; j < 4; j++) {
                aw0[oct][j] = *(const half8*)(w1p + (size_t)((((ky * 2 + oct) * 4 + j) * 2 + 0)) * 1024 + l * 16);
                aw1[oct][j] = *(const half8*)(w1p + (size_t)((((ky * 2 + oct) * 4 + j) * 2 + 1)) * 1024 + l * 16);
            }
#pragma unroll
        for (int r = 0; r < 4; r++) {
            const char* base = sm + (rbase + r + ky) * 1280;
#pragma unroll
            for (int j = 0; j < 4; j++) {
                int p2 = pxt * 16 + c + 2 * j + (g >> 1);
                half8 bh = *(const half8*)(base + swz32(p2 * 32 + (g & 1) * 16));
#pragma unroll
                for (int oct = 0; oct < 2; oct++) {
                    acc[oct][r] = __builtin_amdgcn_mfma_f32_16x16x32_f16(aw0[oct][j], bh, acc[oct][r], 0, 0, 0);
                    acc[oct][r] = __builtin_amdgcn_mfma_f32_16x16x32_f16(aw1[oct][j], bh, acc[oct][r], 0, 0, 0);
                }
            }
        }
    }
    __syncthreads();
    // ---- pass 2: lo plane, term wh*xl ----
    for (int q = t; q < 1120; q += 256) {
        int slab = q / 80, c2 = q % 80;
        int px = c2 >> 1, s = c2 & 1;
        int gy = refl(ystart + slab - 3);
        int gx = refl(x0 + px - 3);
        *(int4*)(sm + slab * 1280 + swz32(px * 32 + s * 16)) =
            *(const int4*)(nl + ((size_t)gy * IMG + gx) * 32 + s * 16);
    }
    __syncthreads();
#pragma unroll 1
    for (int ky = 0; ky < 7; ky++) {
        half8 aw0[2][4];
#pragma unroll
        for (int oct = 0; oct < 2; oct++)
#pragma unroll
            for (int j = 0; j < 4; j++)
                aw0[oct][j] = *(const half8*)(w1p + (size_t)((((ky * 2 + oct) * 4 + j) * 2 + 0)) * 1024 + l * 16);
#pragma unroll
        for (int r = 0; r < 4; r++) {
            const char* base = sm + (rbase + r + ky) * 1280;
#pragma unroll
            for (int j = 0; j < 4; j++) {
                int p2 = pxt * 16 + c + 2 * j + (g >> 1);
                half8 bl = *(const half8*)(base + swz32(p2 * 32 + (g & 1) * 16));
#pragma unroll
                for (int oct = 0; oct < 2; oct++)
                    acc[oct][r] = __builtin_amdgcn_mfma_f32_16x16x32_f16(aw0[oct][j], bl, acc[oct][r], 0, 0, 0);
            }
        }
    }
#pragma unroll
    for (int r = 0; r < 4; r++) {
        int y = ystart + rbase + r;
        if (y < e1) {
            int x = x0 + pxt * 16 + c, ybuf = y - a1;
#pragma unroll
            for (int oct = 0; oct < 2; oct++) {
                ushort4 hv, lv;
                float vv[4];
#pragma unroll
                for (int i = 0; i < 4; i++) {
                    int oc = oct * 16 + g * 4 + i;
                    float v = acc[oct][r][i] * 4.f + b1[oc];
                    vv[i] = fmaxf(v, 0.f) * 0.125f;
                }
                _Float16 h0 = (_Float16)vv[0], h1_ = (_Float16)vv[1], h2_ = (_Float16)vv[2], h3 = (_Float16)vv[3];
                hv.x = h2b(h0); hv.y = h2b(h1_); hv.z = h2b(h2_); hv.w = h2b(h3);
                lv.x = h2b((_Float16)(vv[0] - (float)h0)); lv.y = h2b((_Float16)(vv[1] - (float)h1_));
                lv.z = h2b((_Float16)(vv[2] - (float)h2_)); lv.w = h2b((_Float16)(vv[3] - (float)h3));
                size_t ob = ((size_t)ybuf * IMG + x) * 64 + oct * 32 + g * 8;
                *(ushort4*)(h1h + ob) = hv;
                *(ushort4*)(h1l + ob) = lv;
            }
        }
    }
}

// ---------------------------------------------------------------------------
// conv2 MFMA: 32 -> 32, 5x5 reflect. Two passes over one LDS plane.
// ---------------------------------------------------------------------------
__global__ __launch_bounds__(256, 4) void conv2_mfma(
    const char* __restrict__ h1h, const char* __restrict__ h1l,
    const char* __restrict__ w2p, const float* __restrict__ b2,
    char* __restrict__ h2h, char* __restrict__ h2l,
    int a1, int e1, int a2, int e2)
{
    __shared__ __align__(16) char sm[12 * 2304];  // 12 slabs x 36px x 64B, one plane
    const int t = threadIdx.x, l = t & 63, w = t >> 6;
    const int c = l & 15, g = l >> 4;
    const int x0 = blockIdx.x * 32;
    const int ystart = a2 + blockIdx.y * 8;
    const int pxt = w & 1, rbase = (w >> 1) * 4;

    f32x4 zero4 = {0.f, 0.f, 0.f, 0.f};
    f32x4 acc[2][4];
#pragma unroll
    for (int o = 0; o < 2; o++)
#pragma unroll
        for (int r = 0; r < 4; r++) acc[o][r] = zero4;

    // ---- pass 1: hi plane ----
    for (int q = t; q < 1728; q += 256) {
        int slab = q / 144, c2 = q % 144;
        int px = c2 >> 2, s = c2 & 3;
        int yy = iclamp(refl(ystart + slab - 2), a1, e1 - 1) - a1;
        int gx = refl(x0 + px - 2);
        *(int4*)(sm + slab * 2304 + swz64(px * 64 + s * 16)) =
            *(const int4*)(h1h + ((size_t)yy * IMG + gx) * 64 + s * 16);
    }
    __syncthreads();
#pragma unroll 1
    for (int ky = 0; ky < 5; ky++) {
        half8 aw0[2][5], aw1[2][5];
#pragma unroll
        for (int oct = 0; oct < 2; oct++)
#pragma unroll
            for (int kx = 0; kx < 5; kx++) {
                aw0[oct][kx] = *(const half8*)(w2p + (size_t)((((ky * 2 + oct) * 5 + kx) * 2 + 0)) * 1024 + l * 16);
                aw1[oct][kx] = *(const half8*)(w2p + (size_t)((((ky * 2 + oct) * 5 + kx) * 2 + 1)) * 1024 + l * 16);
            }
#pragma unroll
        for (int r = 0; r < 4; r++) {
            const char* base = sm + (rbase + r + ky) * 2304;
#pragma unroll
            for (int kx = 0; kx < 5; kx++) {
                half8 bh = *(const half8*)(base + swz64((pxt * 16 + c + kx) * 64 + g * 16));
#pragma unroll
                for (int oct = 0; oct < 2; oct++) {
                    acc[oct][r] = __builtin_amdgcn_mfma_f32_16x16x32_f16(aw0[oct][kx], bh, acc[oct][r], 0, 0, 0);
                    acc[oct][r] = __builtin_amdgcn_mfma_f32_16x16x32_f16(aw1[oct][kx], bh, acc[oct][r], 0, 0, 0);
                }
            }
        }
    }
    __syncthreads();
    // ---- pass 2: lo plane ----
    for (int q = t; q < 1728; q += 256) {
        int slab = q / 144, c2 = q % 144;
        int px = c2 >> 2, s = c2 & 3;
        int yy = iclamp(refl(ystart + slab - 2), a1, e1 - 1) - a1;
        int gx = refl(x0 + px - 2);
        *(int4*)(sm + slab * 2304 + swz64(px * 64 + s * 16)) =
            *(const int4*)(h1l + ((size_t)yy * IMG + gx) * 64 + s * 16);
    }
    __syncthreads();
#pragma unroll 1
    for (int ky = 0; ky < 5; ky++) {
        half8 aw0[2][5];
#pragma unroll
        for (int oct = 0; oct < 2; oct++)
#pragma unroll
            for (int kx = 0; kx < 5; kx++)
                aw0[oct][kx] = *(const half8*)(w2p + (size_t)((((ky * 2 + oct) * 5 + kx) * 2 + 0)) * 1024 + l * 16);
#pragma unroll
        for (int r = 0; r < 4; r++) {
            const char* base = sm + (rbase + r + ky) * 2304;
#pragma unroll
            for (int kx = 0; kx < 5; kx++) {
                half8 bl = *(const half8*)(base + swz64((pxt * 16 + c + kx) * 64 + g * 16));
#pragma unroll
                for (int oct = 0; oct < 2; oct++)
                    acc[oct][r] = __builtin_amdgcn_mfma_f32_16x16x32_f16(aw0[oct][kx], bl, acc[oct][r], 0, 0, 0);
            }
        }
    }
#pragma unroll
    for (int r = 0; r < 4; r++) {
        int y = ystart + rbase + r;
        if (y < e2) {
            int x = x0 + pxt * 16 + c, ybuf = y - a2;
#pragma unroll
            for (int oct = 0; oct < 2; oct++) {
                ushort4 hv, lv;
                float vv[4];
#pragma unroll
                for (int i = 0; i < 4; i++) {
                    int oc = oct * 16 + g * 4 + i;
                    float v = acc[oct][r][i] * 8.f + b2[oc];
                    vv[i] = fmaxf(v, 0.f) * 0.125f;
                }
                _Float16 h0 = (_Float16)vv[0], h1_ = (_Float16)vv[1], h2_ = (_Float16)vv[2], h3 = (_Float16)vv[3];
                hv.x = h2b(h0); hv.y = h2b(h1_); hv.z = h2b(h2_); hv.w = h2b(h3);
                lv.x = h2b((_Float16)(vv[0] - (float)h0)); lv.y = h2b((_Float16)(vv[1] - (float)h1_));
                lv.z = h2b((_Float16)(vv[2] - (float)h2_)); lv.w = h2b((_Float16)(vv[3] - (float)h3));
                size_t ob = ((size_t)ybuf * IMG + x) * 64 + oct * 32 + g * 8;
                *(ushort4*)(h2h + ob) = hv;
                *(ushort4*)(h2l + ob) = lv;
            }
        }
    }
}

// ---------------------------------------------------------------------------
// conv3 MFMA: 32 -> 8 (oc padded 16), 5x5 reflect. Two passes, fp32 logits.
// ---------------------------------------------------------------------------
__global__ __launch_bounds__(256, 4) void conv3_mfma(
    const char* __restrict__ h2h, const char* __restrict__ h2l,
    const char* __restrict__ w3p, const float* __restrict__ b3,
    float* __restrict__ lg, int a2, int e2, int r0, int r1, int rowsL)
{
    __shared__ __align__(16) char sm[12 * 2304];
    const int t = threadIdx.x, l = t & 63, w = t >> 6;
    const int c = l & 15, g = l >> 4;
    const int x0 = blockIdx.x * 32;
    const int ystart = r0 + blockIdx.y * 8;
    const int pxt = w & 1, rbase = (w >> 1) * 4;

    f32x4 zero4 = {0.f, 0.f, 0.f, 0.f};
    f32x4 acc[4];
#pragma unroll
    for (int r = 0; r < 4; r++) acc[r] = zero4;

    // ---- pass 1: hi plane ----
    for (int q = t; q < 1728; q += 256) {
        int slab = q / 144, c2 = q % 144;
        int px = c2 >> 2, s = c2 & 3;
        int yy = iclamp(refl(ystart + slab - 2), a2, e2 - 1) - a2;
        int gx = refl(x0 + px - 2);
        *(int4*)(sm + slab * 2304 + swz64(px * 64 + s * 16)) =
            *(const int4*)(h2h + ((size_t)yy * IMG + gx) * 64 + s * 16);
    }
    __syncthreads();
#pragma unroll 1
    for (int ky = 0; ky < 5; ky++) {
        half8 aw0[5], aw1[5];
#pragma unroll
        for (int kx = 0; kx < 5; kx++) {
            aw0[kx] = *(const half8*)(w3p + (size_t)(((ky * 5 + kx) * 2 + 0)) * 1024 + l * 16);
            aw1[kx] = *(const half8*)(w3p + (size_t)(((ky * 5 + kx) * 2 + 1)) * 1024 + l * 16);
        }
#pragma unroll
        for (int r = 0; r < 4; r++) {
            const char* base = sm + (rbase + r + ky) * 2304;
#pragma unroll
            for (int kx = 0; kx < 5; kx++) {
                half8 bh = *(const half8*)(base + swz64((pxt * 16 + c + kx) * 64 + g * 16));
                acc[r] = __builtin_amdgcn_mfma_f32_16x16x32_f16(aw0[kx], bh, acc[r], 0, 0, 0);
                acc[r] = __builtin_amdgcn_mfma_f32_16x16x32_f16(aw1[kx], bh, acc[r], 0, 0, 0);
            }
        }
    }
    __syncthreads();
    // ---- pass 2: lo plane ----
    for (int q = t; q < 1728; q += 256) {
        int slab = q / 144, c2 = q % 144;
        int px = c2 >> 2, s = c2 & 3;
        int yy = iclamp(refl(ystart + slab - 2), a2, e2 - 1) - a2;
        int gx = refl(x0 + px - 2);
        *(int4*)(sm + slab * 2304 + swz64(px * 64 + s * 16)) =
            *(const int4*)(h2l + ((size_t)yy * IMG + gx) * 64 + s * 16);
    }
    __syncthreads();
#pragma unroll 1
    for (int ky = 0; ky < 5; ky++) {
        half8 aw0[5];
#pragma unroll
        for (int kx = 0; kx < 5; kx++)
            aw0[kx] = *(const half8*)(w3p + (size_t)(((ky * 5 + kx) * 2 + 0)) * 1024 + l * 16);
#pragma unroll
        for (int r = 0; r < 4; r++) {
            const char* base = sm + (rbase + r + ky) * 2304;
#pragma unroll
            for (int kx = 0; kx < 5; kx++) {
                half8 bl = *(const half8*)(base + swz64((pxt * 16 + c + kx) * 64 + g * 16));
                acc[r] = __builtin_amdgcn_mfma_f32_16x16x32_f16(aw0[kx], bl, acc[r], 0, 0, 0);
            }
        }
    }
#pragma unroll
    for (int r = 0; r < 4; r++) {
        int y = ystart + rbase + r;
        if (y < r1 && g < 2) {
            int x = x0 + pxt * 16 + c, row = y - r0;
#pragma unroll
            for (int i = 0; i < 4; i++) {
                int oc = g * 4 + i;
                lg[((size_t)oc * rowsL + row) * IMG + x] = acc[r][i] * 8.f + b3[oc];
            }
        }
    }
}

// ---------------------------------------------------------------------------
// final: softmax(logits/5) + depthwise 7x7 zero-pad preconv + weighted sum +
// albedo remodulate. (fp32, unchanged.)
// ---------------------------------------------------------------------------
__global__ __launch_bounds__(256, 2) void final_kernel(
    const float* __restrict__ in, const float* __restrict__ lg, const float* __restrict__ dw,
    float* __restrict__ outp, int ylo, int yhi, int rowsL)
{
    __shared__ __align__(16) float sC[3][22][72];
    __shared__ __align__(16) float sdw[8][49];
    const int t = threadIdx.x;
    const int tx = t & 15, ty = t >> 4;
    const int x0 = blockIdx.x * 64;
    const int y0 = ylo + blockIdx.y * 16;

    for (int e = t; e < 8 * 49; e += 256) sdw[e / 49][e % 49] = dw[e];
    for (int e = t; e < 3 * 22 * 70; e += 256) {
        int c = e / (22 * 70), rem = e % (22 * 70);
        int r = rem / 70, cc = rem % 70;
        int gy = y0 + r - 3, gx = x0 + cc - 3;
        float v = 0.f;
        if (gy >= 0 && gy < IMG && gx >= 0 && gx < IMG) {
            float a = afix(in[(size_t)(c + 3) * IMG * IMG + (size_t)gy * IMG + gx]);
            v = in[(size_t)c * IMG * IMG + (size_t)gy * IMG + gx] / a;
        }
        sC[c][r][cc] = v;
    }
    __syncthreads();
    const int y = y0 + ty;
    if (y >= yhi) return;

    float lv[4][8];
#pragma unroll
    for (int k = 0; k < 8; k++) {
        float4 v = *(const float4*)&lg[((size_t)k * rowsL + (y - ylo)) * IMG + x0 + tx * 4];
        lv[0][k] = v.x; lv[1][k] = v.y; lv[2][k] = v.z; lv[3][k] = v.w;
    }
    float p[4][8];
#pragma unroll
    for (int j = 0; j < 4; j++) {
        float m = -3.4e38f;
#pragma unroll
        for (int k = 0; k < 8; k++) m = fmaxf(m, lv[j][k]);
        float s = 0.f;
#pragma unroll
        for (int k = 0; k < 8; k++) { float ev = __expf((lv[j][k] - m) * 0.2f); p[j][k] = ev; s += ev; }
        float invs = 1.0f / s;
#pragma unroll
        for (int k = 0; k < 8; k++) p[j][k] *= invs;
    }

    float filt[3][4];
#pragma unroll
    for (int c = 0; c < 3; c++)
#pragma unroll
        for (int j = 0; j < 4; j++) filt[c][j] = 0.f;

#pragma unroll 1
    for (int ky = 0; ky < 7; ky++) {
        float cv[3][10];
#pragma unroll
        for (int c = 0; c < 3; c++)
#pragma unroll
            for (int jj = 0; jj < 10; jj++) cv[c][jj] = sC[c][ty + ky][tx * 4 + jj];
#pragma unroll
        for (int kx = 0; kx < 7; kx++) {
            float dwv[8];
#pragma unroll
            for (int k = 0; k < 8; k++) dwv[k] = sdw[k][ky * 7 + kx];
#pragma unroll
            for (int j = 0; j < 4; j++) {
                float e0 = 0.f;
#pragma unroll
                for (int k = 0; k < 8; k++) e0 = fmaf(p[j][k], dwv[k], e0);
#pragma unroll
                for (int c = 0; c < 3; c++) filt[c][j] = fmaf(e0, cv[c][kx + j], filt[c][j]);
            }
        }
    }
#pragma unroll
    for (int c = 0; c < 3; c++) {
        const float* ap = &in[(size_t)(c + 3) * IMG * IMG + (size_t)y * IMG + x0 + tx * 4];
        float4 a4 = *(const float4*)ap;
        float4 o4 = make_float4(afix(a4.x) * filt[c][0], afix(a4.y) * filt[c][1],
                                afix(a4.z) * filt[c][2], afix(a4.w) * filt[c][3]);
        *(float4*)&outp[(size_t)c * IMG * IMG + (size_t)y * IMG + x0 + tx * 4] = o4;
    }
}

// ---------------------------------------------------------------------------
extern "C" void kernel_launch(void* const* d_in, const int* in_sizes, int n_in,
                              void* d_out, int out_size, void* d_ws, size_t ws_size,
                              hipStream_t stream)
{
    const float* in  = (const float*)d_in[0];
    const float* w1  = (const float*)d_in[1];
    const float* b1  = (const float*)d_in[2];
    const float* w2  = (const float*)d_in[3];
    const float* b2  = (const float*)d_in[4];
    const float* w3  = (const float*)d_in[5];
    const float* b3  = (const float*)d_in[6];
    const float* dw  = (const float*)d_in[7];
    float* out = (float*)d_out;

    const size_t WB1 = 112 * 1024, WB2 = 100 * 1024, WB3 = 50 * 1024;
    const size_t NETIN = (size_t)IMG * IMG * 32;  // bytes per plane

    int S = 1024;
    while (S > 64) {
        size_t need = WB1 + WB2 + WB3 + 2 * NETIN
                    + 2ull * (S + 8) * IMG * 64 + 2ull * (S + 4) * IMG * 64
                    + (size_t)S * IMG * 8 * 4;
        if (need <= ws_size) break;
        S >>= 1;
    }
    const int rows1 = S + 8, rows2 = S + 4, rowsL = S;

    char* w1p = (char*)d_ws;
    char* w2p = w1p + WB1;
    char* w3p = w2p + WB2;
    char* nh  = w3p + WB3;
    char* nl  = nh + NETIN;
    char* h1h = nl + NETIN;
    char* h1l = h1h + (size_t)rows1 * IMG * 64;
    char* h2h = h1l + (size_t)rows1 * IMG * 64;
    char* h2l = h2h + (size_t)rows2 * IMG * 64;
    float* lgb = (float*)(h2l + (size_t)rows2 * IMG * 64);

    wprep_kernel<<<66, 256, 0, stream>>>(w1, w2, w3, w1p, w2p, w3p);

    for (int b = 0; b < 4; b++) {
        const float* inb = in + (size_t)b * 12 * IMG * IMG;
        float* outb = out + (size_t)b * 3 * IMG * IMG;
        netin_kernel<<<IMG * IMG / 256, 256, 0, stream>>>(inb, nh, nl);
        for (int r0 = 0; r0 < IMG; r0 += S) {
            int r1 = r0 + S; if (r1 > IMG) r1 = IMG;
            int a1 = r0 - 4; if (a1 < 0) a1 = 0;
            int e1 = r1 + 4; if (e1 > IMG) e1 = IMG;
            int a2 = r0 - 2; if (a2 < 0) a2 = 0;
            int e2 = r1 + 2; if (e2 > IMG) e2 = IMG;
            conv1_mfma<<<dim3(32, (e1 - a1 + 7) / 8), 256, 0, stream>>>(nh, nl, w1p, b1, h1h, h1l, a1, e1);
            conv2_mfma<<<dim3(32, (e2 - a2 + 7) / 8), 256, 0, stream>>>(h1h, h1l, w2p, b2, h2h, h2l, a1, e1, a2, e2);
            conv3_mfma<<<dim3(32, (r1 - r0 + 7) / 8), 256, 0, stream>>>(h2h, h2l, w3p, b3, lgb, a2, e2, r0, r1, rowsL);
            final_kernel<<<dim3(16, (r1 - r0 + 15) / 16), 256, 0, stream>>>(inb, lgb, dw, outb, r0, r1, rowsL);
        }
    }
}